// Round 1
// baseline (1414.794 us; speedup 1.0000x reference)
//
#include <hip/hip_runtime.h>
#include <stdint.h>

// ---------------------------------------------------------------------------
// TransformerBlock fused pipeline for MI355X (gfx950), bf16 MFMA path.
//   B=1024, P=9, D=2700, DFF=512.  M = B*P = 9216 rows.
//   N packed = 8192 (q:0..2699, k:2700..5399, v:5400..8099, pad to 8192)
//   K1 padded 2700->2752 (x @ W), K2 = 1024 exactly ([H1|H2] @ [[WC1],[WC2]])
// ---------------------------------------------------------------------------

#define MROWS  9216
#define NCOLS  8192
#define KP1    2752
#define KP2    1024
#define DMODEL 2700

typedef __bf16 bf16x8 __attribute__((ext_vector_type(8)));
typedef float  f32x4  __attribute__((ext_vector_type(4)));

__device__ __forceinline__ float b2f(unsigned short u) {
  union { unsigned int u; float f; } v; v.u = ((unsigned int)u) << 16; return v.f;
}
__device__ __forceinline__ unsigned short f2b(float f) {
  union { float f; unsigned int u; } v; v.f = f;
  unsigned int r = v.u + 0x7FFFu + ((v.u >> 16) & 1u);   // RNE
  return (unsigned short)(r >> 16);
}

// async global->LDS, 16B per lane (wave-uniform base + lane*16)
__device__ __forceinline__ void gl2lds16(const void* g, void* l) {
  __builtin_amdgcn_global_load_lds(
      (const __attribute__((address_space(1))) void*)g,
      (__attribute__((address_space(3))) void*)l, 16, 0, 0);
}

// ---------------------------------------------------------------------------
// conversion / packing kernels
// ---------------------------------------------------------------------------

// state fp32 [9216][2700] -> Xb bf16 [9216][2752] (zero K-pad)
__global__ void cvt_x(const float* __restrict__ src, unsigned short* __restrict__ dst) {
  int idx = blockIdx.x * 256 + threadIdx.x;            // exact grid: 9216*2752/256
  int r = idx / KP1;
  int c = idx - r * KP1;
  float v = (c < DMODEL) ? src[(size_t)r * DMODEL + c] : 0.f;
  dst[idx] = f2b(v);
}

// H1,H2 fp32 [9216][512] -> Hb bf16 [9216][1024]
__global__ void cvt_h(const float* __restrict__ H1, const float* __restrict__ H2,
                      unsigned short* __restrict__ dst) {
  int idx = blockIdx.x * 256 + threadIdx.x;            // exact grid: 9216*1024/256
  int r = idx >> 10, c = idx & 1023;
  float v = (c < 512) ? H1[r * 512 + c] : H2[r * 512 + (c - 512)];
  dst[idx] = f2b(v);
}

// Wq/Wk/Wv fp32 [2700][2700] -> Wt bf16 [8192][2752], Wt[n][k] = Wsec[k][d]
__global__ void cvt_wqkv(const float* __restrict__ Wq, const float* __restrict__ Wk,
                         const float* __restrict__ Wv, unsigned short* __restrict__ Wt) {
  __shared__ float tile[32][33];
  int k0 = blockIdx.x * 32, n0 = blockIdx.y * 32;      // grid (86, 256), block (32,8)
  int tx = threadIdx.x, ty = threadIdx.y;
#pragma unroll
  for (int s = 0; s < 4; s++) {
    int kk = k0 + ty + 8 * s, nn = n0 + tx;
    float v = 0.f;
    if (kk < DMODEL && nn < 3 * DMODEL) {
      int sec = (nn >= 5400) ? 2 : ((nn >= 2700) ? 1 : 0);
      int d = nn - sec * DMODEL;
      const float* W = (sec == 0) ? Wq : ((sec == 1) ? Wk : Wv);
      v = W[(size_t)kk * DMODEL + d];
    }
    tile[ty + 8 * s][tx] = v;
  }
  __syncthreads();
#pragma unroll
  for (int s = 0; s < 4; s++) {
    int nn = n0 + ty + 8 * s, kk = k0 + tx;
    Wt[(size_t)nn * KP1 + kk] = f2b(tile[tx][ty + 8 * s]);
  }
}

// WC1*/WC2* fp32 [512][2700] -> WCt bf16 [8192][1024], rows k<512 = WC1, k>=512 = WC2
__global__ void cvt_wc(const float* __restrict__ C1q, const float* __restrict__ C1k,
                       const float* __restrict__ C1v, const float* __restrict__ C2q,
                       const float* __restrict__ C2k, const float* __restrict__ C2v,
                       unsigned short* __restrict__ Wt) {
  __shared__ float tile[32][33];
  int k0 = blockIdx.x * 32, n0 = blockIdx.y * 32;      // grid (32, 256), block (32,8)
  int tx = threadIdx.x, ty = threadIdx.y;
#pragma unroll
  for (int s = 0; s < 4; s++) {
    int kk = k0 + ty + 8 * s, nn = n0 + tx;
    float v = 0.f;
    if (nn < 3 * DMODEL) {
      int sec = (nn >= 5400) ? 2 : ((nn >= 2700) ? 1 : 0);
      int d = nn - sec * DMODEL;
      const float* W;
      int kr = kk;
      if (kk < 512) {
        W = (sec == 0) ? C1q : ((sec == 1) ? C1k : C1v);
      } else {
        W = (sec == 0) ? C2q : ((sec == 1) ? C2k : C2v);
        kr = kk - 512;
      }
      v = W[(size_t)kr * DMODEL + d];
    }
    tile[ty + 8 * s][tx] = v;
  }
  __syncthreads();
#pragma unroll
  for (int s = 0; s < 4; s++) {
    int nn = n0 + ty + 8 * s, kk = k0 + tx;
    Wt[(size_t)nn * KP2 + kk] = f2b(tile[tx][ty + 8 * s]);
  }
}

// ---------------------------------------------------------------------------
// GEMM: C[m][n] = sum_k A[m][k] * Bt[n][k]
// 128x128 block tile, BK=64, 4 waves (2x2) each 64x64 via 4x4 of 16x16x32 MFMA.
// global_load_lds staging with XOR swizzle on 16B blocks (2-way max bank alias).
// FUSE=1: epilogue reads main bf16, applies biases + elementwise modulation,
//         writes qkv bf16 in place (same index read/written by same thread).
// ---------------------------------------------------------------------------
template <int FUSE>
__global__ __launch_bounds__(256, 2) void gemm_bt(
    const unsigned short* __restrict__ A,    // [MROWS][Kp]
    const unsigned short* __restrict__ Bt,   // [NCOLS][Kp]
    unsigned short* C,                       // [MROWS][NCOLS]
    const unsigned short* Cmain,             // FUSE=1: main (may alias C)
    const float* __restrict__ bq_, const float* __restrict__ bk_, const float* __restrict__ bv_,
    const float* __restrict__ b1q, const float* __restrict__ b1k, const float* __restrict__ b1v,
    const float* __restrict__ b2q, const float* __restrict__ b2k, const float* __restrict__ b2v,
    int Kp)
{
  __shared__ __align__(16) unsigned short As[128 * 64];
  __shared__ __align__(16) unsigned short Bs[128 * 64];
  const int tid = threadIdx.x;
  const int wave = tid >> 6, lane = tid & 63;
  const int m0 = blockIdx.y * 128, n0 = blockIdx.x * 128;
  const int wm = (wave >> 1) * 64, wn = (wave & 1) * 64;
  const int lm = lane & 15, lq = lane >> 4, l7 = lane & 7;

  // staging: 1024 16B-blocks per tile; thread handles phys blocks r*256+tid.
  // phys block p holds logical (row = p>>3, kblk = (p&7) ^ (row&7)).
  size_t aoff[4], boff[4];
  unsigned int ldsoff[4];
#pragma unroll
  for (int r = 0; r < 4; r++) {
    int p = r * 256 + tid;
    int row = p >> 3;
    int cl = (p & 7) ^ (row & 7);
    aoff[r] = (size_t)(m0 + row) * Kp + cl * 8;
    boff[r] = (size_t)(n0 + row) * Kp + cl * 8;
    ldsoff[r] = (unsigned int)p * 8;   // ushort elements (=16B blocks)
  }

  f32x4 acc[4][4];
#pragma unroll
  for (int i = 0; i < 4; i++)
#pragma unroll
    for (int j = 0; j < 4; j++) acc[i][j] = (f32x4){0.f, 0.f, 0.f, 0.f};

  for (int k0 = 0; k0 < Kp; k0 += 64) {
#pragma unroll
    for (int r = 0; r < 4; r++) {
      gl2lds16(A + aoff[r] + k0, As + ldsoff[r]);
      gl2lds16(Bt + boff[r] + k0, Bs + ldsoff[r]);
    }
    __syncthreads();
#pragma unroll
    for (int c = 0; c < 2; c++) {
      bf16x8 af[4], bfr[4];
      const int kc = c * 4 + lq;
      const int kx = kc ^ l7;
#pragma unroll
      for (int t = 0; t < 4; t++) {
        af[t]  = *(const bf16x8*)(As + (((wm + t * 16 + lm) << 3) + kx) * 8);
        bfr[t] = *(const bf16x8*)(Bs + (((wn + t * 16 + lm) << 3) + kx) * 8);
      }
#pragma unroll
      for (int mt = 0; mt < 4; mt++)
#pragma unroll
        for (int nt = 0; nt < 4; nt++)
          acc[mt][nt] = __builtin_amdgcn_mfma_f32_16x16x32_bf16(
              af[mt], bfr[nt], acc[mt][nt], 0, 0, 0);
    }
    __syncthreads();
  }

  if (FUSE == 0) {
#pragma unroll
    for (int mt = 0; mt < 4; mt++) {
#pragma unroll
      for (int nt = 0; nt < 4; nt++) {
        int gc = n0 + wn + nt * 16 + lm;
        int grb = m0 + wm + mt * 16 + lq * 4;       // C/D: col=lane&15, row=quad*4+i
#pragma unroll
        for (int i = 0; i < 4; i++)
          C[(size_t)(grb + i) * NCOLS + gc] = f2b(acc[mt][nt][i]);
      }
    }
  } else {
#pragma unroll
    for (int nt = 0; nt < 4; nt++) {
      int gc = n0 + wn + nt * 16 + lm;
      if (gc < 3 * DMODEL) {
        int sec = (gc >= 5400) ? 2 : ((gc >= 2700) ? 1 : 0);
        int d = gc - sec * DMODEL;
        const float* bm = (sec == 0) ? bq_ : ((sec == 1) ? bk_ : bv_);
        const float* u1 = (sec == 0) ? b1q : ((sec == 1) ? b1k : b1v);
        const float* u2 = (sec == 0) ? b2q : ((sec == 1) ? b2k : b2v);
        float bmv  = bm[d];
        float bmod = u1[d] + u2[d];
#pragma unroll
        for (int mt = 0; mt < 4; mt++) {
          int grb = m0 + wm + mt * 16 + lq * 4;
#pragma unroll
          for (int i = 0; i < 4; i++) {
            size_t idx = (size_t)(grb + i) * NCOLS + gc;
            float mainv = b2f(Cmain[idx]);
            C[idx] = f2b((mainv + bmv) * (acc[mt][nt][i] + bmod));
          }
        }
      }
    }
  }
}

// ---------------------------------------------------------------------------
// Fused attention (9x9) + softmax + residual + LayerNorm. One block per batch.
// ---------------------------------------------------------------------------
__global__ __launch_bounds__(256) void attn_ln(
    const unsigned short* __restrict__ qkv,  // [9216][8192] bf16 (q|k|v packed)
    const float* __restrict__ x,             // [9216][2700] fp32
    const float* __restrict__ gamma, const float* __restrict__ beta,
    float* __restrict__ out)                 // [9216][2700] fp32
{
  __shared__ unsigned short vlds[9 * DMODEL];  // 48.6 KB
  __shared__ float sc[81];
  __shared__ float red[8];
  const int b = blockIdx.x;
  const int tid = threadIdx.x, wave = tid >> 6, lane = tid & 63;
  const unsigned short* qb = qkv + (size_t)b * 9 * NCOLS;

  // stage V rows into LDS (coalesced)
  for (int j = 0; j < 9; j++)
    for (int d = tid; d < DMODEL; d += 256)
      vlds[j * DMODEL + d] = qb[j * NCOLS + 5400 + d];

  // scores: one wave per (i,j) pair, ushort4 vector loads, shuffle reduce
  for (int p = wave; p < 81; p += 4) {
    int i = p / 9, j = p - i * 9;
    const ushort4* q4 = (const ushort4*)(qb + i * NCOLS);
    const ushort4* k4 = (const ushort4*)(qb + j * NCOLS + DMODEL);
    float s = 0.f;
    for (int dv = lane; dv < 675; dv += 64) {       // 675 = 2700/4
      ushort4 qq = q4[dv], kk = k4[dv];
      s += b2f(qq.x) * b2f(kk.x) + b2f(qq.y) * b2f(kk.y)
         + b2f(qq.z) * b2f(kk.z) + b2f(qq.w) * b2f(kk.w);
    }
#pragma unroll
    for (int off = 32; off > 0; off >>= 1) s += __shfl_down(s, off, 64);
    if (lane == 0) sc[p] = s * 0.019245008972987526f;  // 1/sqrt(2700)
  }
  __syncthreads();

  // softmax over each 9-wide row (thread t < 9 handles row t)
  if (tid < 9) {
    float mx = -1e30f;
#pragma unroll
    for (int j = 0; j < 9; j++) mx = fmaxf(mx, sc[tid * 9 + j]);
    float e[9];
    float sum = 0.f;
#pragma unroll
    for (int j = 0; j < 9; j++) { e[j] = __expf(sc[tid * 9 + j] - mx); sum += e[j]; }
    float inv = 1.f / sum;
#pragma unroll
    for (int j = 0; j < 9; j++) sc[tid * 9 + j] = e[j] * inv;
  }
  __syncthreads();

  // attn + residual + layernorm, one row at a time (whole block per row)
  for (int i = 0; i < 9; i++) {
    float aw[9];
#pragma unroll
    for (int j = 0; j < 9; j++) aw[j] = sc[i * 9 + j];
    const float* xr = x + (size_t)(b * 9 + i) * DMODEL;
    float vals[11];
    float sum = 0.f, sq = 0.f;
    int u = 0;
    for (int d = tid; d < DMODEL; d += 256, u++) {
      float t = xr[d];
#pragma unroll
      for (int j = 0; j < 9; j++) t += aw[j] * b2f(vlds[j * DMODEL + d]);
      vals[u] = t;
      sum += t;
      sq += t * t;
    }
#pragma unroll
    for (int off = 32; off > 0; off >>= 1) {
      sum += __shfl_down(sum, off, 64);
      sq  += __shfl_down(sq,  off, 64);
    }
    __syncthreads();   // protect red[] reuse across rows
    if (lane == 0) { red[wave] = sum; red[4 + wave] = sq; }
    __syncthreads();
    float ts = red[0] + red[1] + red[2] + red[3];
    float tq = red[4] + red[5] + red[6] + red[7];
    float mu = ts * (1.f / 2700.f);
    float rstd = rsqrtf(tq * (1.f / 2700.f) - mu * mu + 1e-5f);
    float* orow = out + (size_t)(b * 9 + i) * DMODEL;
    u = 0;
    for (int d = tid; d < DMODEL; d += 256, u++)
      orow[d] = (vals[u] - mu) * rstd * gamma[d] + beta[d];
  }
}

// ---------------------------------------------------------------------------
extern "C" void kernel_launch(void* const* d_in, const int* in_sizes, int n_in,
                              void* d_out, int out_size, void* d_ws, size_t ws_size,
                              hipStream_t stream) {
  const float* state = (const float*)d_in[0];
  const float* H1    = (const float*)d_in[1];
  const float* H2    = (const float*)d_in[2];
  const float* Wq    = (const float*)d_in[3];
  const float* bq    = (const float*)d_in[4];
  const float* Wk    = (const float*)d_in[5];
  const float* bk    = (const float*)d_in[6];
  const float* Wv    = (const float*)d_in[7];
  const float* bv    = (const float*)d_in[8];
  const float* WC1q  = (const float*)d_in[9];
  const float* bC1q  = (const float*)d_in[10];
  const float* WC1k  = (const float*)d_in[11];
  const float* bC1k  = (const float*)d_in[12];
  const float* WC1v  = (const float*)d_in[13];
  const float* bC1v  = (const float*)d_in[14];
  const float* WC2q  = (const float*)d_in[15];
  const float* bC2q  = (const float*)d_in[16];
  const float* WC2k  = (const float*)d_in[17];
  const float* bC2k  = (const float*)d_in[18];
  const float* WC2v  = (const float*)d_in[19];
  const float* bC2v  = (const float*)d_in[20];
  const float* gamma = (const float*)d_in[21];
  const float* beta  = (const float*)d_in[22];
  float* out = (float*)d_out;

  // workspace layout (all offsets 256B aligned), total 282,460,160 B
  char* ws = (char*)d_ws;
  unsigned short* Xb  = (unsigned short*)(ws + 0);            // 9216*2752*2 = 50,724,864
  unsigned short* Wt  = (unsigned short*)(ws + 50724864);     // 8192*2752*2 = 45,088,768
  unsigned short* Hb  = (unsigned short*)(ws + 95813632);     // 9216*1024*2 = 18,874,368
  unsigned short* WCt = (unsigned short*)(ws + 114688000);    // 8192*1024*2 = 16,777,216
  unsigned short* MQ  = (unsigned short*)(ws + 131465216);    // 9216*8192*2 = 150,994,944

  // 1) convert / pack
  cvt_x<<<dim3(MROWS * KP1 / 256), dim3(256), 0, stream>>>(state, Xb);
  cvt_wqkv<<<dim3(KP1 / 32, NCOLS / 32), dim3(32, 8), 0, stream>>>(Wq, Wk, Wv, Wt);
  cvt_h<<<dim3(MROWS * KP2 / 256), dim3(256), 0, stream>>>(H1, H2, Hb);
  cvt_wc<<<dim3(KP2 / 32, NCOLS / 32), dim3(32, 8), 0, stream>>>(WC1q, WC1k, WC1v,
                                                                 WC2q, WC2k, WC2v, WCt);

  // 2) main projections: MQ = Xb @ Wt^T  (bf16 out)
  gemm_bt<0><<<dim3(NCOLS / 128, MROWS / 128), dim3(256), 0, stream>>>(
      Xb, Wt, MQ, MQ, bq, bk, bv, bC1q, bC1k, bC1v, bC2q, bC2k, bC2v, KP1);

  // 3) modulation projections + fused elementwise: MQ <- (MQ+b)*(Hb@WCt^T + bc)
  gemm_bt<1><<<dim3(NCOLS / 128, MROWS / 128), dim3(256), 0, stream>>>(
      Hb, WCt, MQ, MQ, bq, bk, bv, bC1q, bC1k, bC1v, bC2q, bC2k, bC2v, KP2);

  // 4) attention + softmax + residual + layernorm
  attn_ln<<<dim3(1024), dim3(256), 0, stream>>>(MQ, state, gamma, beta, out);
}

// Round 2
// 1107.374 us; speedup vs baseline: 1.2776x; 1.2776x over previous
//
#include <hip/hip_runtime.h>
#include <stdint.h>

// ---------------------------------------------------------------------------
// TransformerBlock fused pipeline for MI355X (gfx950), bf16 MFMA path.
//   B=1024, P=9, D=2700, DFF=512.  M = B*P = 9216 rows.
//   N packed = 8192 (q:0..2699, k:2700..5399, v:5400..8099, pad to 8192)
//   K1 padded 2700->2752 (x @ W), K2 = 1024 exactly ([H1|H2] @ [[WC1],[WC2]])
// Round 2: single fused GEMM (modulation K=1024 then main K=2752, epilogue
//          combines in registers — saves 300 MB of MQ round-trip), and a
//          rewritten attn_ln (MFMA scores, 9-rows-at-once AV+LN, ~2 KB LDS).
// ---------------------------------------------------------------------------

#define MROWS  9216
#define NCOLS  8192
#define KP1    2752
#define KP2    1024
#define DMODEL 2700

typedef __bf16 bf16x8 __attribute__((ext_vector_type(8)));
typedef float  f32x4  __attribute__((ext_vector_type(4)));

__device__ __forceinline__ float b2f(unsigned short u) {
  union { unsigned int u; float f; } v; v.u = ((unsigned int)u) << 16; return v.f;
}
__device__ __forceinline__ unsigned short f2b(float f) {
  union { float f; unsigned int u; } v; v.f = f;
  unsigned int r = v.u + 0x7FFFu + ((v.u >> 16) & 1u);   // RNE
  return (unsigned short)(r >> 16);
}

// async global->LDS, 16B per lane (wave-uniform base + lane*16)
__device__ __forceinline__ void gl2lds16(const void* g, void* l) {
  __builtin_amdgcn_global_load_lds(
      (const __attribute__((address_space(1))) void*)g,
      (__attribute__((address_space(3))) void*)l, 16, 0, 0);
}

// ---------------------------------------------------------------------------
// conversion / packing kernels (unchanged from round 1)
// ---------------------------------------------------------------------------

__global__ void cvt_x(const float* __restrict__ src, unsigned short* __restrict__ dst) {
  int idx = blockIdx.x * 256 + threadIdx.x;
  int r = idx / KP1;
  int c = idx - r * KP1;
  float v = (c < DMODEL) ? src[(size_t)r * DMODEL + c] : 0.f;
  dst[idx] = f2b(v);
}

__global__ void cvt_h(const float* __restrict__ H1, const float* __restrict__ H2,
                      unsigned short* __restrict__ dst) {
  int idx = blockIdx.x * 256 + threadIdx.x;
  int r = idx >> 10, c = idx & 1023;
  float v = (c < 512) ? H1[r * 512 + c] : H2[r * 512 + (c - 512)];
  dst[idx] = f2b(v);
}

__global__ void cvt_wqkv(const float* __restrict__ Wq, const float* __restrict__ Wk,
                         const float* __restrict__ Wv, unsigned short* __restrict__ Wt) {
  __shared__ float tile[32][33];
  int k0 = blockIdx.x * 32, n0 = blockIdx.y * 32;
  int tx = threadIdx.x, ty = threadIdx.y;
#pragma unroll
  for (int s = 0; s < 4; s++) {
    int kk = k0 + ty + 8 * s, nn = n0 + tx;
    float v = 0.f;
    if (kk < DMODEL && nn < 3 * DMODEL) {
      int sec = (nn >= 5400) ? 2 : ((nn >= 2700) ? 1 : 0);
      int d = nn - sec * DMODEL;
      const float* W = (sec == 0) ? Wq : ((sec == 1) ? Wk : Wv);
      v = W[(size_t)kk * DMODEL + d];
    }
    tile[ty + 8 * s][tx] = v;
  }
  __syncthreads();
#pragma unroll
  for (int s = 0; s < 4; s++) {
    int nn = n0 + ty + 8 * s, kk = k0 + tx;
    Wt[(size_t)nn * KP1 + kk] = f2b(tile[tx][ty + 8 * s]);
  }
}

__global__ void cvt_wc(const float* __restrict__ C1q, const float* __restrict__ C1k,
                       const float* __restrict__ C1v, const float* __restrict__ C2q,
                       const float* __restrict__ C2k, const float* __restrict__ C2v,
                       unsigned short* __restrict__ Wt) {
  __shared__ float tile[32][33];
  int k0 = blockIdx.x * 32, n0 = blockIdx.y * 32;
  int tx = threadIdx.x, ty = threadIdx.y;
#pragma unroll
  for (int s = 0; s < 4; s++) {
    int kk = k0 + ty + 8 * s, nn = n0 + tx;
    float v = 0.f;
    if (nn < 3 * DMODEL) {
      int sec = (nn >= 5400) ? 2 : ((nn >= 2700) ? 1 : 0);
      int d = nn - sec * DMODEL;
      const float* W;
      int kr = kk;
      if (kk < 512) {
        W = (sec == 0) ? C1q : ((sec == 1) ? C1k : C1v);
      } else {
        W = (sec == 0) ? C2q : ((sec == 1) ? C2k : C2v);
        kr = kk - 512;
      }
      v = W[(size_t)kr * DMODEL + d];
    }
    tile[ty + 8 * s][tx] = v;
  }
  __syncthreads();
#pragma unroll
  for (int s = 0; s < 4; s++) {
    int nn = n0 + ty + 8 * s, kk = k0 + tx;
    Wt[(size_t)nn * KP2 + kk] = f2b(tile[tx][ty + 8 * s]);
  }
}

// ---------------------------------------------------------------------------
// Fused double GEMM:
//   phase A: mod  = Hb(9216x1024) @ WCt^T(8192x1024)   -> saved packed bf16
//   phase B: main = Xb(9216x2752) @ Wt^T(8192x2752)
//   epilogue: MQ = (main + bmain) * (mod + bmod)  (bf16)
// 128x128 tile, BK=64, 4 waves (2x2) each 64x64 via 4x4 of 16x16x32 MFMA.
// global_load_lds width=16 with XOR swizzle on 16B blocks.
// ---------------------------------------------------------------------------
__global__ __launch_bounds__(256, 2) void gemm_fused(
    const unsigned short* __restrict__ Xb,
    const unsigned short* __restrict__ Wt,
    const unsigned short* __restrict__ Hb,
    const unsigned short* __restrict__ WCt,
    unsigned short* __restrict__ MQ,
    const float* __restrict__ bq_, const float* __restrict__ bk_, const float* __restrict__ bv_,
    const float* __restrict__ b1q, const float* __restrict__ b1k, const float* __restrict__ b1v,
    const float* __restrict__ b2q, const float* __restrict__ b2k, const float* __restrict__ b2v)
{
  __shared__ __align__(16) unsigned short As[128 * 64];
  __shared__ __align__(16) unsigned short Bs[128 * 64];
  const int tid = threadIdx.x;
  const int wave = tid >> 6, lane = tid & 63;
  const int m0 = blockIdx.y * 128, n0 = blockIdx.x * 128;
  const int wm = (wave >> 1) * 64, wn = (wave & 1) * 64;
  const int lm = lane & 15, lq = lane >> 4, l7 = lane & 7;

  // staging geometry: phys block p = r*256+tid holds logical row p>>3,
  // k-block (p&7)^(row&7); offsets in ushort elements.
  int prow[4], pcl[4];
  unsigned int ldsoff[4];
#pragma unroll
  for (int r = 0; r < 4; r++) {
    int p = r * 256 + tid;
    prow[r] = p >> 3;
    pcl[r] = ((p & 7) ^ (prow[r] & 7)) * 8;
    ldsoff[r] = (unsigned int)p * 8;
  }

  f32x4 acc[4][4];
#pragma unroll
  for (int i = 0; i < 4; i++)
#pragma unroll
    for (int j = 0; j < 4; j++) acc[i][j] = (f32x4){0.f, 0.f, 0.f, 0.f};

  // ---------------- phase A: modulation GEMM, K = 1024 ----------------
  for (int k0 = 0; k0 < KP2; k0 += 64) {
#pragma unroll
    for (int r = 0; r < 4; r++) {
      gl2lds16(Hb + (size_t)(m0 + prow[r]) * KP2 + pcl[r] + k0, As + ldsoff[r]);
      gl2lds16(WCt + (size_t)(n0 + prow[r]) * KP2 + pcl[r] + k0, Bs + ldsoff[r]);
    }
    __syncthreads();
#pragma unroll
    for (int c = 0; c < 2; c++) {
      bf16x8 af[4], bfr[4];
      const int kx = (c * 4 + lq) ^ l7;
#pragma unroll
      for (int t = 0; t < 4; t++) {
        af[t]  = *(const bf16x8*)(As + (((wm + t * 16 + lm) << 3) + kx) * 8);
        bfr[t] = *(const bf16x8*)(Bs + (((wn + t * 16 + lm) << 3) + kx) * 8);
      }
#pragma unroll
      for (int mt = 0; mt < 4; mt++)
#pragma unroll
        for (int nt = 0; nt < 4; nt++)
          acc[mt][nt] = __builtin_amdgcn_mfma_f32_16x16x32_bf16(
              af[mt], bfr[nt], acc[mt][nt], 0, 0, 0);
    }
    __syncthreads();
  }

  // save modulation (+ bias) packed bf16; reset acc
  unsigned int modp[4][4][2];
#pragma unroll
  for (int nt = 0; nt < 4; nt++) {
    int gc = n0 + wn + nt * 16 + lm;
    float bmod = 0.f;
    if (gc < 3 * DMODEL) {
      int sec = (gc >= 5400) ? 2 : ((gc >= 2700) ? 1 : 0);
      int d = gc - sec * DMODEL;
      const float* u1 = (sec == 0) ? b1q : ((sec == 1) ? b1k : b1v);
      const float* u2 = (sec == 0) ? b2q : ((sec == 1) ? b2k : b2v);
      bmod = u1[d] + u2[d];
    }
#pragma unroll
    for (int mt = 0; mt < 4; mt++) {
#pragma unroll
      for (int h = 0; h < 2; h++) {
        unsigned int lo = f2b(acc[mt][nt][2 * h] + bmod);
        unsigned int hi = f2b(acc[mt][nt][2 * h + 1] + bmod);
        modp[mt][nt][h] = lo | (hi << 16);
      }
    }
  }
#pragma unroll
  for (int i = 0; i < 4; i++)
#pragma unroll
    for (int j = 0; j < 4; j++) acc[i][j] = (f32x4){0.f, 0.f, 0.f, 0.f};

  // ---------------- phase B: main GEMM, K = 2752 ----------------
  for (int k0 = 0; k0 < KP1; k0 += 64) {
#pragma unroll
    for (int r = 0; r < 4; r++) {
      gl2lds16(Xb + (size_t)(m0 + prow[r]) * KP1 + pcl[r] + k0, As + ldsoff[r]);
      gl2lds16(Wt + (size_t)(n0 + prow[r]) * KP1 + pcl[r] + k0, Bs + ldsoff[r]);
    }
    __syncthreads();
#pragma unroll
    for (int c = 0; c < 2; c++) {
      bf16x8 af[4], bfr[4];
      const int kx = (c * 4 + lq) ^ l7;
#pragma unroll
      for (int t = 0; t < 4; t++) {
        af[t]  = *(const bf16x8*)(As + (((wm + t * 16 + lm) << 3) + kx) * 8);
        bfr[t] = *(const bf16x8*)(Bs + (((wn + t * 16 + lm) << 3) + kx) * 8);
      }
#pragma unroll
      for (int mt = 0; mt < 4; mt++)
#pragma unroll
        for (int nt = 0; nt < 4; nt++)
          acc[mt][nt] = __builtin_amdgcn_mfma_f32_16x16x32_bf16(
              af[mt], bfr[nt], acc[mt][nt], 0, 0, 0);
    }
    __syncthreads();
  }

  // ---------------- epilogue: qkv = (main + b) * mod ----------------
#pragma unroll
  for (int nt = 0; nt < 4; nt++) {
    int gc = n0 + wn + nt * 16 + lm;
    float bmv = 0.f;
    if (gc < 3 * DMODEL) {
      int sec = (gc >= 5400) ? 2 : ((gc >= 2700) ? 1 : 0);
      int d = gc - sec * DMODEL;
      const float* bm = (sec == 0) ? bq_ : ((sec == 1) ? bk_ : bv_);
      bmv = bm[d];
    }
#pragma unroll
    for (int mt = 0; mt < 4; mt++) {
      int grb = m0 + wm + mt * 16 + lq * 4;   // C/D: col=lane&15, row=quad*4+i
#pragma unroll
      for (int i = 0; i < 4; i++) {
        float mod = b2f((unsigned short)(modp[mt][nt][i >> 1] >> ((i & 1) * 16)));
        MQ[(size_t)(grb + i) * NCOLS + gc] = f2b((acc[mt][nt][i] + bmv) * mod);
      }
    }
  }
}

// ---------------------------------------------------------------------------
// Fused attention (9x9) + softmax + residual + LayerNorm. One block per batch.
//   phase 1: scores via MFMA, K=2700 split across 4 waves (each byte read once)
//   phase 2: softmax (9 threads)
//   phase 3: all 9 output rows at once per float4-column chunk; t kept packed
//            bf16 in registers; fp32 sum/sumsq accumulators
//   phase 4: one reduction for all 9 rows' mean/var
//   phase 5: vectorized LN write
// ---------------------------------------------------------------------------
__global__ __launch_bounds__(256, 2) void attn_ln(
    const unsigned short* __restrict__ qkv,  // [9216][8192] bf16 (q|k|v packed)
    const float* __restrict__ x,             // [9216][2700] fp32
    const float* __restrict__ gamma, const float* __restrict__ beta,
    float* __restrict__ out)                 // [9216][2700] fp32
{
  __shared__ float part[4][81];
  __shared__ float sc[81];
  __shared__ float redS[4][9], redQ[4][9];
  __shared__ float muL[9], rsL[9];

  const int b = blockIdx.x;
  const int tid = threadIdx.x, wave = tid >> 6, lane = tid & 63;
  const unsigned short* qb = qkv + (size_t)b * 9 * NCOLS;

  // ---- phase 1: scores S[i][j] = q_i . k_j via 16x16x32 MFMA, K-split ----
  {
    const int l15 = lane & 15, lq8 = (lane >> 4) * 8;
    const int rA = (l15 < 9) ? l15 : 8;                 // clamp: rows 9..15 junk
    const unsigned short* qrow = qb + (size_t)rA * NCOLS;          // 16B aligned
    const unsigned short* krow = qb + (size_t)rA * NCOLS + DMODEL; // 8B aligned
    f32x4 accS = (f32x4){0.f, 0.f, 0.f, 0.f};
    for (int s = wave; s < 85; s += 4) {                // 85 = ceil(2700/32)
      int k0 = s * 32 + lq8;
      union { uint2 u[2]; unsigned int w[4]; bf16x8 v; } au, bu;
      au.u[0] = *(const uint2*)(qrow + k0);
      au.u[1] = *(const uint2*)(qrow + k0 + 4);
      bu.u[0] = *(const uint2*)(krow + k0);
      bu.u[1] = *(const uint2*)(krow + k0 + 4);
      if (s == 84) {                                    // mask k >= 2700
#pragma unroll
        for (int wd = 0; wd < 4; wd++)
          if (k0 + 2 * wd >= DMODEL) { au.w[wd] = 0u; bu.w[wd] = 0u; }
      }
      accS = __builtin_amdgcn_mfma_f32_16x16x32_bf16(au.v, bu.v, accS, 0, 0, 0);
    }
#pragma unroll
    for (int i = 0; i < 4; i++) {
      int row = (lane >> 4) * 4 + i, col = l15;
      if (row < 9 && col < 9) part[wave][row * 9 + col] = accS[i];
    }
  }
  __syncthreads();

  if (tid < 81)
    sc[tid] = (part[0][tid] + part[1][tid] + part[2][tid] + part[3][tid])
              * 0.019245008972987526f;                  // 1/sqrt(2700)
  __syncthreads();

  // ---- phase 2: softmax per row (threads 0..8) ----
  if (tid < 9) {
    float mx = -1e30f;
#pragma unroll
    for (int j = 0; j < 9; j++) mx = fmaxf(mx, sc[tid * 9 + j]);
    float e[9], sum = 0.f;
#pragma unroll
    for (int j = 0; j < 9; j++) { e[j] = __expf(sc[tid * 9 + j] - mx); sum += e[j]; }
    float inv = 1.f / sum;
#pragma unroll
    for (int j = 0; j < 9; j++) sc[tid * 9 + j] = e[j] * inv;
  }
  __syncthreads();

  // ---- phase 3: t = x + A.V for all 9 rows, per float4 column-chunk ----
  float sum[9], sq[9];
#pragma unroll
  for (int i = 0; i < 9; i++) { sum[i] = 0.f; sq[i] = 0.f; }
  unsigned int pv[9][3][2];
#pragma unroll
  for (int c = 0; c < 3; c++) {
    int e = tid + c * 256;
    if (e < 675) {                                      // 675 = 2700/4
      float4 t4[9];
#pragma unroll
      for (int i = 0; i < 9; i++)
        t4[i] = ((const float4*)(x + (size_t)(b * 9 + i) * DMODEL))[e];
#pragma unroll
      for (int j = 0; j < 9; j++) {
        ushort4 vv = ((const ushort4*)(qb + (size_t)j * NCOLS + 5400))[e];
        float v0 = b2f(vv.x), v1 = b2f(vv.y), v2 = b2f(vv.z), v3 = b2f(vv.w);
#pragma unroll
        for (int i = 0; i < 9; i++) {
          float p = sc[i * 9 + j];
          t4[i].x += p * v0; t4[i].y += p * v1;
          t4[i].z += p * v2; t4[i].w += p * v3;
        }
      }
#pragma unroll
      for (int i = 0; i < 9; i++) {
        sum[i] += t4[i].x + t4[i].y + t4[i].z + t4[i].w;
        sq[i]  += t4[i].x * t4[i].x + t4[i].y * t4[i].y
                + t4[i].z * t4[i].z + t4[i].w * t4[i].w;
        pv[i][c][0] = (unsigned int)f2b(t4[i].x) | ((unsigned int)f2b(t4[i].y) << 16);
        pv[i][c][1] = (unsigned int)f2b(t4[i].z) | ((unsigned int)f2b(t4[i].w) << 16);
      }
    }
  }

  // ---- phase 4: block reduction for all 9 rows ----
#pragma unroll
  for (int i = 0; i < 9; i++) {
    float s = sum[i], q = sq[i];
#pragma unroll
    for (int off = 32; off > 0; off >>= 1) {
      s += __shfl_down(s, off, 64);
      q += __shfl_down(q, off, 64);
    }
    if (lane == 0) { redS[wave][i] = s; redQ[wave][i] = q; }
  }
  __syncthreads();
  if (tid < 9) {
    float ts = redS[0][tid] + redS[1][tid] + redS[2][tid] + redS[3][tid];
    float tq = redQ[0][tid] + redQ[1][tid] + redQ[2][tid] + redQ[3][tid];
    float mu = ts * (1.f / 2700.f);
    muL[tid] = mu;
    rsL[tid] = rsqrtf(tq * (1.f / 2700.f) - mu * mu + 1e-5f);
  }
  __syncthreads();

  // ---- phase 5: LN write, float4 ----
#pragma unroll
  for (int c = 0; c < 3; c++) {
    int e = tid + c * 256;
    if (e < 675) {
      float4 g = ((const float4*)gamma)[e];
      float4 bb = ((const float4*)beta)[e];
#pragma unroll
      for (int i = 0; i < 9; i++) {
        float m = muL[i], r = rsL[i];
        float t0 = b2f((unsigned short)(pv[i][c][0] & 0xFFFF));
        float t1 = b2f((unsigned short)(pv[i][c][0] >> 16));
        float t2 = b2f((unsigned short)(pv[i][c][1] & 0xFFFF));
        float t3 = b2f((unsigned short)(pv[i][c][1] >> 16));
        float4 o;
        o.x = (t0 - m) * r * g.x + bb.x;
        o.y = (t1 - m) * r * g.y + bb.y;
        o.z = (t2 - m) * r * g.z + bb.z;
        o.w = (t3 - m) * r * g.w + bb.w;
        ((float4*)(out + (size_t)(b * 9 + i) * DMODEL))[e] = o;
      }
    }
  }
}

// ---------------------------------------------------------------------------
extern "C" void kernel_launch(void* const* d_in, const int* in_sizes, int n_in,
                              void* d_out, int out_size, void* d_ws, size_t ws_size,
                              hipStream_t stream) {
  const float* state = (const float*)d_in[0];
  const float* H1    = (const float*)d_in[1];
  const float* H2    = (const float*)d_in[2];
  const float* Wq    = (const float*)d_in[3];
  const float* bq    = (const float*)d_in[4];
  const float* Wk    = (const float*)d_in[5];
  const float* bk    = (const float*)d_in[6];
  const float* Wv    = (const float*)d_in[7];
  const float* bv    = (const float*)d_in[8];
  const float* WC1q  = (const float*)d_in[9];
  const float* bC1q  = (const float*)d_in[10];
  const float* WC1k  = (const float*)d_in[11];
  const float* bC1k  = (const float*)d_in[12];
  const float* WC1v  = (const float*)d_in[13];
  const float* bC1v  = (const float*)d_in[14];
  const float* WC2q  = (const float*)d_in[15];
  const float* bC2q  = (const float*)d_in[16];
  const float* WC2k  = (const float*)d_in[17];
  const float* bC2k  = (const float*)d_in[18];
  const float* WC2v  = (const float*)d_in[19];
  const float* bC2v  = (const float*)d_in[20];
  const float* gamma = (const float*)d_in[21];
  const float* beta  = (const float*)d_in[22];
  float* out = (float*)d_out;

  // workspace layout (256B aligned), total 282,460,160 B
  char* ws = (char*)d_ws;
  unsigned short* Xb  = (unsigned short*)(ws + 0);            // 9216*2752*2
  unsigned short* Wt  = (unsigned short*)(ws + 50724864);     // 8192*2752*2
  unsigned short* Hb  = (unsigned short*)(ws + 95813632);     // 9216*1024*2
  unsigned short* WCt = (unsigned short*)(ws + 114688000);    // 8192*1024*2
  unsigned short* MQ  = (unsigned short*)(ws + 131465216);    // 9216*8192*2

  // 1) convert / pack
  cvt_x<<<dim3(MROWS * KP1 / 256), dim3(256), 0, stream>>>(state, Xb);
  cvt_wqkv<<<dim3(KP1 / 32, NCOLS / 32), dim3(32, 8), 0, stream>>>(Wq, Wk, Wv, Wt);
  cvt_h<<<dim3(MROWS * KP2 / 256), dim3(256), 0, stream>>>(H1, H2, Hb);
  cvt_wc<<<dim3(KP2 / 32, NCOLS / 32), dim3(32, 8), 0, stream>>>(WC1q, WC1k, WC1v,
                                                                 WC2q, WC2k, WC2v, WCt);

  // 2) fused double GEMM: MQ = (Xb@Wt^T + b) * (Hb@WCt^T + bc)
  gemm_fused<<<dim3(NCOLS / 128, MROWS / 128), dim3(256), 0, stream>>>(
      Xb, Wt, Hb, WCt, MQ, bq, bk, bv, bC1q, bC1k, bC1v, bC2q, bC2k, bC2v);

  // 3) attention + softmax + residual + layernorm
  attn_ln<<<dim3(1024), dim3(256), 0, stream>>>(MQ, state, gamma, beta, out);
}